// Round 1
// baseline (395.986 us; speedup 1.0000x reference)
//
#include <hip/hip_runtime.h>
#include <math.h>

#define C 96
#define K 512
#define P_PER_B 110592   // 48*48*48
#define NPOS 221184      // 2 * 110592
#define MT 32            // positions per tile
#define GRID_SIM 1728    // blocks; 4 tiles each (1728*4*32 = 221184)
#define ITERS_SIM 4
#define XROW 104         // fp16 row pad: 208 B rows -> 8 distinct 16B slots mod 128 B

// ---------------------------------------------------------------------------
// Round 8: move the fast pass from fp32 VALU (157 TF ceiling, ~427 us) to
// f16 MFMA (~2 PF). Validated argmax-margin architecture retained:
//   fast pass computes S_k = sum_c f16(x_c)*f16(pn_k,c) in fp32 accum;
//   rigorous worst-case |S_k - x.pn_k| <= 2^-10*||x|| + 7e-6*||x|| + 3e-6
//   (f16 RTNE per-term, exact f16 products in fp32, MFMA fp32 accum, denorm
//   absolutes); numpy side <= 1.8e-5*||x||. tau = 2.2e-3*||x|| + 1e-5 covers
//   2x the sum with ~10% margin -> unflagged argmax provably matches numpy;
//   flagged (~7%) re-resolved bit-exactly by the validated refine kernel.
//
// MFMA orientation: protos on M (A-operand), positions on N (B-operand).
// C/D map (m89-verified): col = lane&15 = POSITION, row = (lane>>4)*4+reg =
// proto-within-tile. Each lane therefore accumulates 32 proto scores for one
// position -> top-2 is an in-lane scan + 2 shfl_xor rounds (masks 16,32).
// A and B fragments use the same (lane>>4, j) -> k map, so any HW k-perm
// cancels. B-side x tile staged in LDS as [pos][c] fp16, row-padded to 104
// (conflict-free ds_read_b128). Per-wave 128 protos * 3 K-frags = 96 VGPRs
// of B held across the whole grid-stride loop (reloaded never).
// ---------------------------------------------------------------------------

typedef _Float16 f16;
typedef _Float16 f16x8 __attribute__((ext_vector_type(8)));
typedef _Float16 f16x4 __attribute__((ext_vector_type(4)));
typedef float f32x4 __attribute__((ext_vector_type(4)));

// Workspace: pnT[96][512] fp32 numpy-exact normalized prototypes (192 KB,
// channel-major, for refine) + pn16[512][96] fp16 (96 KB, proto-major, for
// MFMA B... A fragments).

__global__ __launch_bounds__(256) void prep_kernel(const float* __restrict__ proto,
                                                   float* __restrict__ pnT,
                                                   f16* __restrict__ pn16) {
    int k = blockIdx.x * 256 + threadIdx.x;
    if (k >= K) return;
    const float* row = proto + k * C;
    // numpy pairwise_sum, n=96 <= blocksize: 8 accumulators + fixed combine
    float r[8];
#pragma unroll
    for (int j = 0; j < 8; ++j) r[j] = __fmul_rn(row[j], row[j]);
    for (int i = 8; i < C; i += 8) {
#pragma unroll
        for (int j = 0; j < 8; ++j)
            r[j] = __fadd_rn(r[j], __fmul_rn(row[i + j], row[i + j]));
    }
    float res = __fadd_rn(__fadd_rn(__fadd_rn(r[0], r[1]), __fadd_rn(r[2], r[3])),
                          __fadd_rn(__fadd_rn(r[4], r[5]), __fadd_rn(r[6], r[7])));
    float n = fmaxf(__fsqrt_rn(res), 1e-12f);
    for (int c = 0; c < C; ++c) {
        float v = __fdiv_rn(row[c], n);
        pnT[(size_t)c * K + k] = v;            // exact fp32, channel-major (refine)
        pn16[(size_t)k * C + c] = (f16)v;      // RTNE fp16, proto-major (MFMA)
    }
}

// ---------------------------------------------------------------------------
// Fast pass: f16 MFMA argmax. 256 threads = 4 waves; wave w owns protos
// [w*128, w*128+128) as 8 MFMA M-tiles; per M-tile of 32 positions: 2
// position-sets (N=16 each) x 8 proto-tiles x 3 K-steps = 48 MFMAs.
// ---------------------------------------------------------------------------
__global__ __launch_bounds__(256) void sim_argmax_kernel(
        const float* __restrict__ x,
        const f16* __restrict__ pn16,
        int* __restrict__ out) {
    __shared__ __align__(16) f16 xt[MT * XROW];   // 6656 B, [pos][c] padded
    __shared__ float n2p[8][MT];                  // ||x||^2 partials
    __shared__ float wbv[4][MT], wsv[4][MT];      // per-wave best/second
    __shared__ int   wkv[4][MT];

    const int tid = threadIdx.x;
    const int lane = tid & 63;
    const int w = tid >> 6;          // wave 0..3
    const int l15 = lane & 15;
    const int lg = lane >> 4;        // 0..3 (k-group)

    // ---- A fragments (protos), resident in VGPRs for the whole kernel ----
    // lane l: proto row = w*128 + t*16 + l15, channels c0..c0+7 contiguous.
    f16x8 afr[8][3];
#pragma unroll
    for (int t = 0; t < 8; ++t)
#pragma unroll
        for (int q = 0; q < 3; ++q) {
            int proto = w * 128 + t * 16 + l15;
            int c0 = q * 32 + lg * 8;
            afr[t][q] = *(const f16x8*)(pn16 + (size_t)proto * C + c0);
        }

    const int pos_s = tid & 31;      // staging: position within tile
    const int cg = tid >> 5;         // staging: channel group 0..7 (12 ch each)

#pragma unroll 1
    for (int it = 0; it < ITERS_SIM; ++it) {
        int tile = blockIdx.x + it * GRID_SIM;
        int m0 = tile * MT;          // tiles never straddle batches (110592%32==0)
        int b = (m0 >= P_PER_B) ? 1 : 0;
        int p0 = m0 - b * P_PER_B;
        const float* xb = x + (size_t)b * (size_t)C * P_PER_B + p0;

        __syncthreads();   // prev tile's wbv/n2p readers + xt readers done

        // ---- stage: 12 channels/thread, fp32->fp16, transpose to [pos][c] ----
        float ss = 0.f;
        f16 h[12];
#pragma unroll
        for (int j = 0; j < 12; ++j) {
            float v = xb[(size_t)(cg * 12 + j) * P_PER_B + pos_s];
            ss = fmaf(v, v, ss);
            h[j] = (f16)v;           // RTNE
        }
        n2p[cg][pos_s] = ss;
#pragma unroll
        for (int g = 0; g < 3; ++g) {
            f16x4 hv = { h[g * 4 + 0], h[g * 4 + 1], h[g * 4 + 2], h[g * 4 + 3] };
            *(f16x4*)(xt + pos_s * XROW + cg * 12 + g * 4) = hv;
        }
        __syncthreads();

        // ---- B fragments (positions): lane l -> pos = s*16+l15, 8 ch ----
        f16x8 bfr[2][3];
#pragma unroll
        for (int s = 0; s < 2; ++s)
#pragma unroll
            for (int q = 0; q < 3; ++q)
                bfr[s][q] = *(const f16x8*)(xt + (s * 16 + l15) * XROW + q * 32 + lg * 8);

        // ---- MFMA: D[proto][pos] ----
        f32x4 acc[2][8];
#pragma unroll
        for (int s = 0; s < 2; ++s)
#pragma unroll
            for (int t = 0; t < 8; ++t)
                acc[s][t] = (f32x4){0.f, 0.f, 0.f, 0.f};
#pragma unroll
        for (int t = 0; t < 8; ++t)
#pragma unroll
            for (int q = 0; q < 3; ++q)
#pragma unroll
                for (int s = 0; s < 2; ++s)
                    acc[s][t] = __builtin_amdgcn_mfma_f32_16x16x32_f16(
                        afr[t][q], bfr[s][q], acc[s][t], 0, 0, 0);

        // ---- in-lane top-2: lane holds 32 proto scores per position-set ----
        float bv[2], sv[2];
        int kv[2];
#pragma unroll
        for (int s = 0; s < 2; ++s) { bv[s] = -3.4e38f; sv[s] = -3.4e38f; kv[s] = 0; }
#pragma unroll
        for (int t = 0; t < 8; ++t)
#pragma unroll
            for (int r = 0; r < 4; ++r) {
                int kk = w * 128 + t * 16 + lg * 4 + r;
#pragma unroll
                for (int s = 0; s < 2; ++s) {
                    float v = acc[s][t][r];
                    if (v > bv[s]) { sv[s] = bv[s]; bv[s] = v; kv[s] = kk; }
                    else if (v > sv[s]) sv[s] = v;
                }
            }

        // ---- merge the 4 lanes sharing a position (masks 16, 32) ----
#pragma unroll
        for (int m = 16; m <= 32; m <<= 1)
#pragma unroll
            for (int s = 0; s < 2; ++s) {
                float ob = __shfl_xor(bv[s], m);
                float os = __shfl_xor(sv[s], m);
                int   ok = __shfl_xor(kv[s], m);
                if (ob > bv[s]) { sv[s] = fmaxf(bv[s], os); bv[s] = ob; kv[s] = ok; }
                else            { sv[s] = fmaxf(sv[s], ob); }   // tie -> gap 0 -> flagged
            }
        if (lane < 16) {
#pragma unroll
            for (int s = 0; s < 2; ++s) {
                int pos = s * 16 + l15;
                wbv[w][pos] = bv[s]; wsv[w][pos] = sv[s]; wkv[w][pos] = kv[s];
            }
        }
        __syncthreads();

        // ---- final merge across 4 waves (disjoint proto sets) + tau test ----
        if (tid < MT) {
            float n2 = 0.f;
#pragma unroll
            for (int g = 0; g < 8; ++g) n2 += n2p[g][tid];
            float b_ = wbv[0][tid], s_ = wsv[0][tid];
            int k_ = wkv[0][tid];
#pragma unroll
            for (int ww = 1; ww < 4; ++ww) {
                float ob = wbv[ww][tid], os = wsv[ww][tid];
                int ok = wkv[ww][tid];
                if (ob > b_) { s_ = fmaxf(b_, os); b_ = ob; k_ = ok; }
                else         { s_ = fmaxf(s_, ob); }
            }
            // rigorous: 2*(2^-10 + 7e-6 + 1.8e-5)*||x|| + 7e-6 < tau
            float tau = 2.2e-3f * sqrtf(n2) + 1e-5f;
            out[m0 + tid] = (b_ - s_ < tau) ? (k_ | (int)0x80000000) : k_;
        }
    }
}

// ---------------------------------------------------------------------------
// Refine pass (validated round 3, logic untouched): bit-exact numpy-fp32
// emulation of flagged positions. Segments shrunk 256 -> 64 positions/block
// (grid 3456) to cut the Poisson tail at the ~7% f16 flag rate.
// ---------------------------------------------------------------------------
__global__ __launch_bounds__(256) void refine_kernel(
        const float* __restrict__ x,
        const float* __restrict__ pnT,
        int* __restrict__ out) {
    __shared__ int list[64];
    __shared__ int cnt;
    __shared__ float xn[C];
    __shared__ float nrm_s;
    __shared__ float sc[256];
    __shared__ int ki[256];

    int tid = threadIdx.x;

    if (tid == 0) cnt = 0;
    __syncthreads();

    if (tid < 64) {
        int g = blockIdx.x * 64 + tid;
        if (out[g] < 0) {
            int i = atomicAdd(&cnt, 1);
            list[i] = g;
        }
    }
    __syncthreads();
    int n = cnt;

    for (int i = 0; i < n; ++i) {
        int gg = list[i];
        int b = (gg >= P_PER_B) ? 1 : 0;
        int p = gg - b * P_PER_B;
        const float* xb = x + (size_t)b * (size_t)C * P_PER_B + p;

        if (tid < C) xn[tid] = xb[(size_t)tid * P_PER_B];
        __syncthreads();

        // numpy: norm over non-contiguous axis -> strictly sequential fp32
        if (tid == 0) {
            float acc = __fmul_rn(xn[0], xn[0]);
            for (int c = 1; c < C; ++c)
                acc = __fadd_rn(acc, __fmul_rn(xn[c], xn[c]));
            nrm_s = fmaxf(__fsqrt_rn(acc), 1e-12f);
        }
        __syncthreads();
        if (tid < C) xn[tid] = __fdiv_rn(xn[tid], nrm_s);
        __syncthreads();

        // einsum optimize=False: sequential fp32 mul+add, c ascending, no FMA
        float s0 = 0.f, s1 = 0.f;
        for (int c = 0; c < C; ++c) {
            s0 = __fadd_rn(s0, __fmul_rn(xn[c], pnT[(size_t)c * K + tid]));
            s1 = __fadd_rn(s1, __fmul_rn(xn[c], pnT[(size_t)c * K + tid + 256]));
        }

        float bv = s0;
        int bk = tid;
        if (s1 > bv) { bv = s1; bk = tid + 256; }  // strict: lower index wins ties

        sc[tid] = bv;
        ki[tid] = bk;
        __syncthreads();

        for (int off = 128; off > 0; off >>= 1) {
            if (tid < off) {
                float ov = sc[tid + off];
                int oi = ki[tid + off];
                if (ov > sc[tid] || (ov == sc[tid] && oi < ki[tid])) {
                    sc[tid] = ov;
                    ki[tid] = oi;
                }
            }
            __syncthreads();
        }

        if (tid == 0) out[gg] = ki[0];
        __syncthreads();
    }
}

// ---------------------------------------------------------------------------
extern "C" void kernel_launch(void* const* d_in, const int* in_sizes, int n_in,
                              void* d_out, int out_size, void* d_ws, size_t ws_size,
                              hipStream_t stream) {
    const float* x = (const float*)d_in[0];      // [2,96,48,48,48] fp32
    const float* proto = (const float*)d_in[1];  // [512,96] fp32
    int* out = (int*)d_out;                      // [2,48,48,48] int32

    float* pnT = (float*)d_ws;                        // 96*512*4  = 196608 B
    f16* pn16 = (f16*)((char*)d_ws + 196608);         // 512*96*2  =  98304 B

    prep_kernel<<<2, 256, 0, stream>>>(proto, pnT, pn16);
    sim_argmax_kernel<<<GRID_SIM, 256, 0, stream>>>(x, pn16, out);
    refine_kernel<<<NPOS / 64, 256, 0, stream>>>(x, pnT, out);
}

// Round 7
// 300.162 us; speedup vs baseline: 1.3192x; 1.3192x over previous
//
#include <hip/hip_runtime.h>
#include <math.h>

#define C 96
#define K 512
#define P_PER_B 110592   // 48*48*48
#define NPOS 221184      // 2 * 110592
#define MT 32            // positions per tile
#define ITERS_SIM 2
#define GRID_SIM 3456    // 3456 blocks * 2 tiles * 32 pos = 221184
#define XROW 104         // fp16 row pad: 208 B rows -> conflict-free b128 reads

// ---------------------------------------------------------------------------
// Round 9 (fifth resubmit; rounds 2-6 broker timeouts; source re-audited r5,
// no defects found). Round-8 counters: sim 190us, MfmaUtil 4.4%, VALUBusy
// 27%, Occupancy 11% (~1 wave/SIMD effective), HBM ~0 warm -> pure latency
// exposure: 148 VGPR + 64 acc regs capped residency at ~2 waves/SIMD;
// branchy 64-score top-2 + stage->barrier chains exposed every stall. Fixes:
//  1) occupancy: wave owns 64 protos (afr 48 VGPR, was 96); 8-wave blocks
//     (512 thr) cover K=512; bfr loaded per-q (8 live, was 24); acc 32.
//     __launch_bounds__(512,4) -> <=128 VGPR -> 2 blocks/CU = 4 waves/SIMD.
//  2) branchless top-2: proto index packed into low 9 mantissa bits of the
//     fp32 score; insert = {m2=max(m2,min(m1,v)); m1=max(m1,v)}. Quant error
//     <= 2^-14*||x|| folded into tau (2.35e-3). Ties -> margin~0 -> flagged.
//  3) T14 async stage: next tile's 6 global loads issued right after the
//     stage barrier, consumed next iter (latency hides under MFMA+scan).
// Error budget per side: f16 x,p 2*2^-11=9.8e-4; MFMA accum 6e-6; numpy
// 1.8e-5; pack quant 6.1e-5 (all *||x||) + 1e-5 abs. tau = 2.35e-3*||x||
// + 1e-5 covers 2x with ~10% headroom. Flagged re-resolved bit-exactly.
// ---------------------------------------------------------------------------

typedef _Float16 f16;
typedef _Float16 f16x8 __attribute__((ext_vector_type(8)));
typedef _Float16 f16x2 __attribute__((ext_vector_type(2)));
typedef float f32x4 __attribute__((ext_vector_type(4)));

// Workspace: pnT[96][512] fp32 numpy-exact normalized prototypes (192 KB,
// channel-major, refine) + pn16[512][96] fp16 (96 KB, proto-major, MFMA A).

__global__ __launch_bounds__(256) void prep_kernel(const float* __restrict__ proto,
                                                   float* __restrict__ pnT,
                                                   f16* __restrict__ pn16) {
    int k = blockIdx.x * 256 + threadIdx.x;
    if (k >= K) return;
    const float* row = proto + k * C;
    // numpy pairwise_sum, n=96 <= blocksize: 8 accumulators + fixed combine
    float r[8];
#pragma unroll
    for (int j = 0; j < 8; ++j) r[j] = __fmul_rn(row[j], row[j]);
    for (int i = 8; i < C; i += 8) {
#pragma unroll
        for (int j = 0; j < 8; ++j)
            r[j] = __fadd_rn(r[j], __fmul_rn(row[i + j], row[i + j]));
    }
    float res = __fadd_rn(__fadd_rn(__fadd_rn(r[0], r[1]), __fadd_rn(r[2], r[3])),
                          __fadd_rn(__fadd_rn(r[4], r[5]), __fadd_rn(r[6], r[7])));
    float n = fmaxf(__fsqrt_rn(res), 1e-12f);
    for (int c = 0; c < C; ++c) {
        float v = __fdiv_rn(row[c], n);
        pnT[(size_t)c * K + k] = v;            // exact fp32, channel-major (refine)
        pn16[(size_t)k * C + c] = (f16)v;      // RTNE fp16, proto-major (MFMA)
    }
}

// ---------------------------------------------------------------------------
// Fast pass: f16 MFMA argmax. 512 threads = 8 waves; wave w owns protos
// [w*64, w*64+64) as 4 MFMA M-tiles; 32 positions as 2 N-sets of 16.
// Per tile per wave: 4t x 3q x 2s = 24 MFMAs.
// ---------------------------------------------------------------------------
__global__ __launch_bounds__(512, 4) void sim_argmax_kernel(
        const float* __restrict__ x,
        const f16* __restrict__ pn16,
        int* __restrict__ out) {
    __shared__ __align__(16) f16 xt[MT * XROW];   // 6656 B, [pos][c] padded
    __shared__ float n2p[16][MT];                 // ||x||^2 partials
    __shared__ float wm1[8][MT], wm2[8][MT];      // per-wave packed top-2

    const int tid = threadIdx.x;
    const int lane = tid & 63;
    const int w = tid >> 6;          // wave 0..7
    const int l15 = lane & 15;
    const int lg = lane >> 4;        // 0..3 (k-group)
    const int lg4 = lg << 2;

    // ---- A fragments (64 protos/wave), resident in VGPRs ----
    f16x8 afr[4][3];
#pragma unroll
    for (int t = 0; t < 4; ++t)
#pragma unroll
        for (int q = 0; q < 3; ++q) {
            int proto = w * 64 + t * 16 + l15;
            int c0 = q * 32 + lg * 8;
            afr[t][q] = *(const f16x8*)(pn16 + (size_t)proto * C + c0);
        }

    // staging role: 16 channel-groups x 32 positions, 6 channels each
    const int pos_s = tid & 31;
    const int cg = tid >> 5;         // 0..15

    const int m00 = blockIdx.x * (MT * ITERS_SIM);   // consecutive tiles/block
    const int b = (m00 >= P_PER_B) ? 1 : 0;          // both tiles same batch
    const float* xq = x + (size_t)b * (size_t)C * P_PER_B + (m00 - b * P_PER_B)
                    + (size_t)(cg * 6) * P_PER_B + pos_s;

    // prologue: load tile 0's x into registers
    float fl[6];
#pragma unroll
    for (int j = 0; j < 6; ++j) fl[j] = xq[(size_t)j * P_PER_B];

#pragma unroll
    for (int it = 0; it < ITERS_SIM; ++it) {
        const int m0 = m00 + it * MT;

        __syncthreads();   // prev iter's xt/n2p/wm readers done

        // ---- stage from fl: convert + transpose to [pos][c], norm partial ----
        float ss = 0.f;
        f16 h[6];
#pragma unroll
        for (int j = 0; j < 6; ++j) {
            ss = fmaf(fl[j], fl[j], ss);
            h[j] = (f16)fl[j];       // RTNE
        }
        n2p[cg][pos_s] = ss;
        f16* xw = xt + pos_s * XROW + cg * 6;
        *(f16x2*)(xw + 0) = (f16x2){h[0], h[1]};
        *(f16x2*)(xw + 2) = (f16x2){h[2], h[3]};
        *(f16x2*)(xw + 4) = (f16x2){h[4], h[5]};
        __syncthreads();

        // ---- T14: issue next tile's loads now; waited on at next stage ----
        if (it + 1 < ITERS_SIM) {
#pragma unroll
            for (int j = 0; j < 6; ++j)
                fl[j] = xq[(size_t)j * P_PER_B + (it + 1) * MT];
        }

        // ---- MFMA: D[proto][pos]; B loaded per-q (8 live VGPRs) ----
        f32x4 acc[2][4];
#pragma unroll
        for (int s = 0; s < 2; ++s)
#pragma unroll
            for (int t = 0; t < 4; ++t)
                acc[s][t] = (f32x4){0.f, 0.f, 0.f, 0.f};
#pragma unroll
        for (int q = 0; q < 3; ++q) {
            f16x8 b0 = *(const f16x8*)(xt + l15 * XROW + q * 32 + lg * 8);
            f16x8 b1 = *(const f16x8*)(xt + (16 + l15) * XROW + q * 32 + lg * 8);
#pragma unroll
            for (int t = 0; t < 4; ++t) {
                acc[0][t] = __builtin_amdgcn_mfma_f32_16x16x32_f16(
                    afr[t][q], b0, acc[0][t], 0, 0, 0);
                acc[1][t] = __builtin_amdgcn_mfma_f32_16x16x32_f16(
                    afr[t][q], b1, acc[1][t], 0, 0, 0);
            }
        }

        // ---- branchless packed top-2 (k in low 9 mantissa bits) ----
        float m1[2], m2[2];
        m1[0] = m1[1] = -3.4e38f;
        m2[0] = m2[1] = -3.4e38f;
        const int kb = w * 64 + lg4;
#pragma unroll
        for (int t = 0; t < 4; ++t)
#pragma unroll
            for (int r = 0; r < 4; ++r) {
                const int kk = kb + t * 16 + r;   // folds to and_or + add
#pragma unroll
                for (int s = 0; s < 2; ++s) {
                    float pk = __uint_as_float(
                        (__float_as_uint(acc[s][t][r]) & 0xFFFFFE00u) | (unsigned)kk);
                    m2[s] = fmaxf(m2[s], fminf(m1[s], pk));
                    m1[s] = fmaxf(m1[s], pk);
                }
            }

        // ---- merge the 4 k-groups sharing a position (masks 16, 32) ----
#pragma unroll
        for (int m = 16; m <= 32; m <<= 1)
#pragma unroll
            for (int s = 0; s < 2; ++s) {
                float o1 = __shfl_xor(m1[s], m);
                float o2 = __shfl_xor(m2[s], m);
                m2[s] = fmaxf(fmaxf(m2[s], o2), fminf(m1[s], o1));
                m1[s] = fmaxf(m1[s], o1);
            }
        if (lane < 16) {
            wm1[w][l15] = m1[0];      wm2[w][l15] = m2[0];
            wm1[w][16 + l15] = m1[1]; wm2[w][16 + l15] = m2[1];
        }
        __syncthreads();

        // ---- final merge across 8 waves (disjoint proto sets) + tau test ----
        if (tid < MT) {
            float n2 = 0.f;
#pragma unroll
            for (int g = 0; g < 16; ++g) n2 += n2p[g][tid];
            float b_ = wm1[0][tid], s_ = wm2[0][tid];
#pragma unroll
            for (int ww = 1; ww < 8; ++ww) {
                float o1 = wm1[ww][tid], o2 = wm2[ww][tid];
                s_ = fmaxf(fmaxf(s_, o2), fminf(b_, o1));
                b_ = fmaxf(b_, o1);
            }
            float tau = 2.35e-3f * sqrtf(n2) + 1e-5f;
            int k_ = (int)(__float_as_uint(b_) & 511u);
            out[m0 + tid] = (b_ - s_ < tau) ? (k_ | (int)0x80000000) : k_;
        }
    }
}

// ---------------------------------------------------------------------------
// Refine pass: bit-exact numpy-fp32 emulation of flagged positions.
// 32-position segments (grid 6912, mean ~2.2 flags/block at ~7%) to spread
// the serial per-flag cost; wave-shfl argmax replaces the 8-barrier tree.
// ---------------------------------------------------------------------------
__global__ __launch_bounds__(256) void refine_kernel(
        const float* __restrict__ x,
        const float* __restrict__ pnT,
        int* __restrict__ out) {
    __shared__ int list[MT];
    __shared__ int cnt;
    __shared__ float xn[C];
    __shared__ float nrm_s;
    __shared__ float sval[4];
    __shared__ int sidx[4];

    int tid = threadIdx.x;

    if (tid == 0) cnt = 0;
    __syncthreads();

    if (tid < MT) {
        int g = blockIdx.x * MT + tid;
        if (out[g] < 0) {
            int i = atomicAdd(&cnt, 1);
            list[i] = g;
        }
    }
    __syncthreads();
    int n = cnt;

    for (int i = 0; i < n; ++i) {
        int gg = list[i];
        int b = (gg >= P_PER_B) ? 1 : 0;
        int p = gg - b * P_PER_B;
        const float* xb = x + (size_t)b * (size_t)C * P_PER_B + p;

        if (tid < C) xn[tid] = xb[(size_t)tid * P_PER_B];
        __syncthreads();

        // numpy: norm over non-contiguous axis -> strictly sequential fp32
        if (tid == 0) {
            float acc = __fmul_rn(xn[0], xn[0]);
            for (int c = 1; c < C; ++c)
                acc = __fadd_rn(acc, __fmul_rn(xn[c], xn[c]));
            nrm_s = fmaxf(__fsqrt_rn(acc), 1e-12f);
        }
        __syncthreads();
        if (tid < C) xn[tid] = __fdiv_rn(xn[tid], nrm_s);
        __syncthreads();

        // einsum optimize=False: sequential fp32 mul+add, c ascending, no FMA
        float s0 = 0.f, s1 = 0.f;
        for (int c = 0; c < C; ++c) {
            s0 = __fadd_rn(s0, __fmul_rn(xn[c], pnT[(size_t)c * K + tid]));
            s1 = __fadd_rn(s1, __fmul_rn(xn[c], pnT[(size_t)c * K + tid + 256]));
        }

        float bv = s0;
        int bk = tid;
        if (s1 > bv) { bv = s1; bk = tid + 256; }  // strict: lower index wins ties

        // wave-level argmax (exact compares, min-index tie-break; associative)
#pragma unroll
        for (int off = 1; off < 64; off <<= 1) {
            float ov = __shfl_xor(bv, off);
            int oi = __shfl_xor(bk, off);
            if (ov > bv || (ov == bv && oi < bk)) { bv = ov; bk = oi; }
        }
        int wv = tid >> 6;
        if ((tid & 63) == 0) { sval[wv] = bv; sidx[wv] = bk; }
        __syncthreads();

        if (tid == 0) {
            float fb = sval[0];
            int fk = sidx[0];
            for (int ww = 1; ww < 4; ++ww) {
                if (sval[ww] > fb || (sval[ww] == fb && sidx[ww] < fk)) {
                    fb = sval[ww]; fk = sidx[ww];
                }
            }
            out[gg] = fk;
        }
        __syncthreads();   // protect xn/sval before next flag
    }
}

// ---------------------------------------------------------------------------
extern "C" void kernel_launch(void* const* d_in, const int* in_sizes, int n_in,
                              void* d_out, int out_size, void* d_ws, size_t ws_size,
                              hipStream_t stream) {
    const float* x = (const float*)d_in[0];      // [2,96,48,48,48] fp32
    const float* proto = (const float*)d_in[1];  // [512,96] fp32
    int* out = (int*)d_out;                      // [2,48,48,48] int32

    float* pnT = (float*)d_ws;                        // 96*512*4  = 196608 B
    f16* pn16 = (f16*)((char*)d_ws + 196608);         // 512*96*2  =  98304 B

    prep_kernel<<<2, 256, 0, stream>>>(proto, pnT, pn16);
    sim_argmax_kernel<<<GRID_SIM, 512, 0, stream>>>(x, pn16, out);
    refine_kernel<<<NPOS / MT, 256, 0, stream>>>(x, pnT, out);
}

// Round 8
// 265.194 us; speedup vs baseline: 1.4932x; 1.1319x over previous
//
#include <hip/hip_runtime.h>
#include <math.h>

#define C 96
#define K 512
#define P_PER_B 110592   // 48*48*48
#define NPOS 221184      // 2 * 110592
#define MT 32            // positions per tile
#define ITERS_SIM 4
#define GRID_SIM 1728    // 1728 blocks * 4 tiles * 32 pos = 221184
#define XROW 104         // f16 row pad: 208 B rows -> 2-way (free) LDS banking

// ---------------------------------------------------------------------------
// Round 10. Round-9 profile (300us total, absmax=0): refine = 137us is the
// top dispatch (MfmaUtil 0, VALUBusy 19%, FETCH 39MB) -- ~16k flags at 7.4%
// flag rate, each costing a serial exact re-score; 16k x 196KB pn reads =
// 3.1GB L2 -> ~90us floor even if refine were perfectly parallel. The flag
// COUNT is the lever, not refine structure.
//
// Fix: compensated-f16 fast pass. x,pn split into f16 hi+lo (lo = exact
// Sterbenz residual, rel err 2^-22); S = hi*hi + hi*lo + lo*hi via 3 chained
// MFMAs into one fp32 acc. Error/side: lo-quant ~3*2^-22, MFMA accum <=
// 1.8e-5, numpy <= 1.8e-5, pack quant 6.1e-5 (dominant) -> tau = 2.6e-4*
// ||x|| + 3e-5 (29% headroom) -> ~0.8% flags (~1800) -> refine work /9.
// Refine kernel byte-identical (validated).
//
// Sim pays for 3x MFMA with a 16-wave/1024-thr block, 32 protos/wave:
// afr hi+lo = 48 VGPR (was 96 for 64 protos), acc 16, top-2 scan halves
// to 8 vals/lane/s. ~115 VGPR under __launch_bounds__(1024,4) -> 4 w/SIMD.
// Fragment maps (m89-verified), pack/merge logic, LDS geometry unchanged.
// ---------------------------------------------------------------------------

typedef _Float16 f16;
typedef _Float16 f16x8 __attribute__((ext_vector_type(8)));
typedef float f32x4 __attribute__((ext_vector_type(4)));

// Workspace: pnT[96][512] fp32 numpy-exact (192KB, refine) +
// pn16h[512][96] f16 hi (96KB) + pn16l[512][96] f16 lo (96KB). Total 384KB.

__global__ __launch_bounds__(256) void prep_kernel(const float* __restrict__ proto,
                                                   float* __restrict__ pnT,
                                                   f16* __restrict__ pn16h,
                                                   f16* __restrict__ pn16l) {
    int k = blockIdx.x * 256 + threadIdx.x;
    if (k >= K) return;
    const float* row = proto + k * C;
    // numpy pairwise_sum, n=96 <= blocksize: 8 accumulators + fixed combine
    float r[8];
#pragma unroll
    for (int j = 0; j < 8; ++j) r[j] = __fmul_rn(row[j], row[j]);
    for (int i = 8; i < C; i += 8) {
#pragma unroll
        for (int j = 0; j < 8; ++j)
            r[j] = __fadd_rn(r[j], __fmul_rn(row[i + j], row[i + j]));
    }
    float res = __fadd_rn(__fadd_rn(__fadd_rn(r[0], r[1]), __fadd_rn(r[2], r[3])),
                          __fadd_rn(__fadd_rn(r[4], r[5]), __fadd_rn(r[6], r[7])));
    float n = fmaxf(__fsqrt_rn(res), 1e-12f);
    for (int c = 0; c < C; ++c) {
        float v = __fdiv_rn(row[c], n);
        pnT[(size_t)c * K + k] = v;            // exact fp32, channel-major (refine)
        f16 h = (f16)v;                        // RTNE hi
        pn16h[(size_t)k * C + c] = h;
        pn16l[(size_t)k * C + c] = (f16)(v - (float)h);   // exact residual -> RTNE lo
    }
}

// ---------------------------------------------------------------------------
// Fast pass: compensated f16 MFMA argmax. 1024 threads = 16 waves; wave w
// owns protos [w*32, w*32+32) as 2 M-tiles; 32 positions as 2 N-sets of 16.
// Per tile per wave: 2t x 3q x 2s x 3 terms = 36 MFMAs.
// ---------------------------------------------------------------------------
__global__ __launch_bounds__(1024, 4) void sim_argmax_kernel(
        const float* __restrict__ x,
        const f16* __restrict__ pn16h,
        const f16* __restrict__ pn16l,
        int* __restrict__ out) {
    __shared__ __align__(16) f16 xth[MT * XROW];  // hi plane, [pos][c] padded
    __shared__ __align__(16) f16 xtl[MT * XROW];  // lo plane
    __shared__ float n2p[32][MT];                 // ||x||^2 partials
    __shared__ float wm1[16][MT], wm2[16][MT];    // per-wave packed top-2

    const int tid = threadIdx.x;
    const int lane = tid & 63;
    const int w = tid >> 6;          // wave 0..15
    const int l15 = lane & 15;
    const int lg = lane >> 4;        // 0..3 (k-group)
    const int lg4 = lg << 2;

    // ---- A fragments (32 protos/wave), hi+lo resident in VGPRs ----
    f16x8 afh[2][3], afl[2][3];
#pragma unroll
    for (int t = 0; t < 2; ++t)
#pragma unroll
        for (int q = 0; q < 3; ++q) {
            size_t off = (size_t)(w * 32 + t * 16 + l15) * C + q * 32 + lg * 8;
            afh[t][q] = *(const f16x8*)(pn16h + off);
            afl[t][q] = *(const f16x8*)(pn16l + off);
        }

    // staging role: 32 channel-groups x 32 positions, 3 channels each
    const int pos_s = tid & 31;
    const int cg = tid >> 5;         // 0..31

    const int m00 = blockIdx.x * (MT * ITERS_SIM);   // 110592 % 128 == 0:
    const int b = (m00 >= P_PER_B) ? 1 : 0;          // no batch straddle
    const float* xq = x + (size_t)b * (size_t)C * P_PER_B + (m00 - b * P_PER_B)
                    + (size_t)(cg * 3) * P_PER_B + pos_s;

    // prologue: load tile 0's x into registers
    float fl[3];
#pragma unroll
    for (int j = 0; j < 3; ++j) fl[j] = xq[(size_t)j * P_PER_B];

#pragma unroll 1
    for (int it = 0; it < ITERS_SIM; ++it) {
        const int m0 = m00 + it * MT;

        __syncthreads();   // prev iter's xt/n2p/wm readers done

        // ---- stage hi+lo planes, norm partial ----
        float ss = 0.f;
#pragma unroll
        for (int j = 0; j < 3; ++j) {
            float v = fl[j];
            ss = fmaf(v, v, ss);
            f16 h = (f16)v;                       // RTNE hi
            xth[pos_s * XROW + cg * 3 + j] = h;
            xtl[pos_s * XROW + cg * 3 + j] = (f16)(v - (float)h);   // exact resid
        }
        n2p[cg][pos_s] = ss;
        __syncthreads();

        // ---- T14: issue next tile's loads now; waited on at next stage ----
        if (it != ITERS_SIM - 1) {
#pragma unroll
            for (int j = 0; j < 3; ++j)
                fl[j] = xq[(size_t)j * P_PER_B + (it + 1) * MT];
        }

        // ---- MFMA: D[proto][pos] = hi*hi + hi*lo + lo*hi ----
        f32x4 acc[2][2];
#pragma unroll
        for (int s = 0; s < 2; ++s)
#pragma unroll
            for (int t = 0; t < 2; ++t)
                acc[s][t] = (f32x4){0.f, 0.f, 0.f, 0.f};
#pragma unroll
        for (int q = 0; q < 3; ++q) {
            const int co = q * 32 + lg * 8;
            f16x8 b0h = *(const f16x8*)(xth + l15 * XROW + co);
            f16x8 b1h = *(const f16x8*)(xth + (16 + l15) * XROW + co);
            f16x8 b0l = *(const f16x8*)(xtl + l15 * XROW + co);
            f16x8 b1l = *(const f16x8*)(xtl + (16 + l15) * XROW + co);
#pragma unroll
            for (int t = 0; t < 2; ++t) {
                acc[0][t] = __builtin_amdgcn_mfma_f32_16x16x32_f16(afh[t][q], b0h, acc[0][t], 0, 0, 0);
                acc[0][t] = __builtin_amdgcn_mfma_f32_16x16x32_f16(afh[t][q], b0l, acc[0][t], 0, 0, 0);
                acc[0][t] = __builtin_amdgcn_mfma_f32_16x16x32_f16(afl[t][q], b0h, acc[0][t], 0, 0, 0);
                acc[1][t] = __builtin_amdgcn_mfma_f32_16x16x32_f16(afh[t][q], b1h, acc[1][t], 0, 0, 0);
                acc[1][t] = __builtin_amdgcn_mfma_f32_16x16x32_f16(afh[t][q], b1l, acc[1][t], 0, 0, 0);
                acc[1][t] = __builtin_amdgcn_mfma_f32_16x16x32_f16(afl[t][q], b1h, acc[1][t], 0, 0, 0);
            }
        }

        // ---- branchless packed top-2 (k in low 9 mantissa bits) ----
        float m1[2], m2[2];
        m1[0] = m1[1] = -3.4e38f;
        m2[0] = m2[1] = -3.4e38f;
        const int kb = w * 32 + lg4;
#pragma unroll
        for (int t = 0; t < 2; ++t)
#pragma unroll
            for (int r = 0; r < 4; ++r) {
                const int kk = kb + t * 16 + r;   // folds to and_or + add
#pragma unroll
                for (int s = 0; s < 2; ++s) {
                    float pk = __uint_as_float(
                        (__float_as_uint(acc[s][t][r]) & 0xFFFFFE00u) | (unsigned)kk);
                    m2[s] = fmaxf(m2[s], fminf(m1[s], pk));
                    m1[s] = fmaxf(m1[s], pk);
                }
            }

        // ---- merge the 4 k-groups sharing a position (masks 16, 32) ----
#pragma unroll
        for (int m = 16; m <= 32; m <<= 1)
#pragma unroll
            for (int s = 0; s < 2; ++s) {
                float o1 = __shfl_xor(m1[s], m);
                float o2 = __shfl_xor(m2[s], m);
                m2[s] = fmaxf(fmaxf(m2[s], o2), fminf(m1[s], o1));
                m1[s] = fmaxf(m1[s], o1);
            }
        if (lane < 16) {
            wm1[w][l15] = m1[0];      wm2[w][l15] = m2[0];
            wm1[w][16 + l15] = m1[1]; wm2[w][16 + l15] = m2[1];
        }
        __syncthreads();

        // ---- final merge across 16 waves (disjoint proto sets) + tau ----
        if (tid < MT) {
            float n2 = 0.f;
#pragma unroll
            for (int g = 0; g < 32; ++g) n2 += n2p[g][tid];
            float b_ = wm1[0][tid], s_ = wm2[0][tid];
#pragma unroll
            for (int ww = 1; ww < 16; ++ww) {
                float o1 = wm1[ww][tid], o2 = wm2[ww][tid];
                s_ = fmaxf(fmaxf(s_, o2), fminf(b_, o1));
                b_ = fmaxf(b_, o1);
            }
            // tau >= 2*(pack 6.1e-5 + fast 2.2e-5 + numpy 1.8e-5) = 2.02e-4
            float tau = 2.6e-4f * sqrtf(n2) + 3e-5f;
            int k_ = (int)(__float_as_uint(b_) & 511u);
            out[m0 + tid] = (b_ - s_ < tau) ? (k_ | (int)0x80000000) : k_;
        }
    }
}

// ---------------------------------------------------------------------------
// Refine pass (byte-identical to validated round-9 version): bit-exact
// numpy-fp32 emulation of flagged positions. ~1800 flags expected now.
// ---------------------------------------------------------------------------
__global__ __launch_bounds__(256) void refine_kernel(
        const float* __restrict__ x,
        const float* __restrict__ pnT,
        int* __restrict__ out) {
    __shared__ int list[MT];
    __shared__ int cnt;
    __shared__ float xn[C];
    __shared__ float nrm_s;
    __shared__ float sval[4];
    __shared__ int sidx[4];

    int tid = threadIdx.x;

    if (tid == 0) cnt = 0;
    __syncthreads();

    if (tid < MT) {
        int g = blockIdx.x * MT + tid;
        if (out[g] < 0) {
            int i = atomicAdd(&cnt, 1);
            list[i] = g;
        }
    }
    __syncthreads();
    int n = cnt;

    for (int i = 0; i < n; ++i) {
        int gg = list[i];
        int b = (gg >= P_PER_B) ? 1 : 0;
        int p = gg - b * P_PER_B;
        const float* xb = x + (size_t)b * (size_t)C * P_PER_B + p;

        if (tid < C) xn[tid] = xb[(size_t)tid * P_PER_B];
        __syncthreads();

        // numpy: norm over non-contiguous axis -> strictly sequential fp32
        if (tid == 0) {
            float acc = __fmul_rn(xn[0], xn[0]);
            for (int c = 1; c < C; ++c)
                acc = __fadd_rn(acc, __fmul_rn(xn[c], xn[c]));
            nrm_s = fmaxf(__fsqrt_rn(acc), 1e-12f);
        }
        __syncthreads();
        if (tid < C) xn[tid] = __fdiv_rn(xn[tid], nrm_s);
        __syncthreads();

        // einsum optimize=False: sequential fp32 mul+add, c ascending, no FMA
        float s0 = 0.f, s1 = 0.f;
        for (int c = 0; c < C; ++c) {
            s0 = __fadd_rn(s0, __fmul_rn(xn[c], pnT[(size_t)c * K + tid]));
            s1 = __fadd_rn(s1, __fmul_rn(xn[c], pnT[(size_t)c * K + tid + 256]));
        }

        float bv = s0;
        int bk = tid;
        if (s1 > bv) { bv = s1; bk = tid + 256; }  // strict: lower index wins ties

        // wave-level argmax (exact compares, min-index tie-break; associative)
#pragma unroll
        for (int off = 1; off < 64; off <<= 1) {
            float ov = __shfl_xor(bv, off);
            int oi = __shfl_xor(bk, off);
            if (ov > bv || (ov == bv && oi < bk)) { bv = ov; bk = oi; }
        }
        int wv = tid >> 6;
        if ((tid & 63) == 0) { sval[wv] = bv; sidx[wv] = bk; }
        __syncthreads();

        if (tid == 0) {
            float fb = sval[0];
            int fk = sidx[0];
            for (int ww = 1; ww < 4; ++ww) {
                if (sval[ww] > fb || (sval[ww] == fb && sidx[ww] < fk)) {
                    fb = sval[ww]; fk = sidx[ww];
                }
            }
            out[gg] = fk;
        }
        __syncthreads();   // protect xn/sval before next flag
    }
}

// ---------------------------------------------------------------------------
extern "C" void kernel_launch(void* const* d_in, const int* in_sizes, int n_in,
                              void* d_out, int out_size, void* d_ws, size_t ws_size,
                              hipStream_t stream) {
    const float* x = (const float*)d_in[0];      // [2,96,48,48,48] fp32
    const float* proto = (const float*)d_in[1];  // [512,96] fp32
    int* out = (int*)d_out;                      // [2,48,48,48] int32

    float* pnT = (float*)d_ws;                        // 96*512*4  = 196608 B
    f16* pn16h = (f16*)((char*)d_ws + 196608);        // 512*96*2  =  98304 B
    f16* pn16l = (f16*)((char*)d_ws + 294912);        // 512*96*2  =  98304 B

    prep_kernel<<<2, 256, 0, stream>>>(proto, pnT, pn16h, pn16l);
    sim_argmax_kernel<<<GRID_SIM, 1024, 0, stream>>>(x, pn16h, pn16l, out);
    refine_kernel<<<NPOS / MT, 256, 0, stream>>>(x, pnT, out);
}

// Round 11
// 253.322 us; speedup vs baseline: 1.5632x; 1.0469x over previous
//
#include <hip/hip_runtime.h>
#include <math.h>

#define C 96
#define K 512
#define P_PER_B 110592   // 48*48*48
#define NPOS 221184      // 2 * 110592
#define MT 64            // positions per tile (4 MFMA N-sets)
#define ITERS_SIM 2
#define GRID_SIM 1728    // 1728 blocks * 2 tiles * 64 pos = 221184
#define CB 12            // 8-channel blocks (C = 96 = 12*8)

// ---------------------------------------------------------------------------
// Round 11 (second resubmit; rounds 9-10 broker timeouts; audited twice, no
// defects). Round-10 profile (265us, absmax=0): sim top at 114us with
// BANK_CONFLICT 9.29M (was 995K): scalar 2-byte staging stores at 208-B row
// stride are 4-way conflicted; MfmaUtil 23% (3-term compensation chains
// 9-deep into 4 acc regs); 2 barriers per 32-pos tile. Fixes:
//  1) cblock-major LDS [cb][pos][8]: staging = one ds_write_b128 per plane
//     per thread (wave=channel-block, lane=pos); reads b128 tile all 32
//     banks at the bandwidth minimum; shift-only addressing.
//  2) MT=64: 8 independent acc chains (4s x 2t); hh/lh/hl phases issue 8
//     independent MFMAs between dependent touches of one register; half the
//     barriers/merges per position.
//  3) refine: 4-wave-parallel flag processing (math bit-identical).
// Error budget unchanged from r10 (absmax=0 validated): tau = 2.6e-4*||x||
// + 3e-5; flagged (~0.8%) re-resolved bit-exactly.
// ---------------------------------------------------------------------------

typedef _Float16 f16;
typedef _Float16 f16x8 __attribute__((ext_vector_type(8)));
typedef float f32x4 __attribute__((ext_vector_type(4)));

// Workspace: pnT[96][512] fp32 numpy-exact (192KB, refine) +
// pn16h[512][96] f16 hi (96KB) + pn16l[512][96] f16 lo (96KB). Total 384KB.

__global__ __launch_bounds__(256) void prep_kernel(const float* __restrict__ proto,
                                                   float* __restrict__ pnT,
                                                   f16* __restrict__ pn16h,
                                                   f16* __restrict__ pn16l) {
    int k = blockIdx.x * 256 + threadIdx.x;
    if (k >= K) return;
    const float* row = proto + k * C;
    // numpy pairwise_sum, n=96 <= blocksize: 8 accumulators + fixed combine
    float r[8];
#pragma unroll
    for (int j = 0; j < 8; ++j) r[j] = __fmul_rn(row[j], row[j]);
    for (int i = 8; i < C; i += 8) {
#pragma unroll
        for (int j = 0; j < 8; ++j)
            r[j] = __fadd_rn(r[j], __fmul_rn(row[i + j], row[i + j]));
    }
    float res = __fadd_rn(__fadd_rn(__fadd_rn(r[0], r[1]), __fadd_rn(r[2], r[3])),
                          __fadd_rn(__fadd_rn(r[4], r[5]), __fadd_rn(r[6], r[7])));
    float n = fmaxf(__fsqrt_rn(res), 1e-12f);
    for (int c = 0; c < C; ++c) {
        float v = __fdiv_rn(row[c], n);
        pnT[(size_t)c * K + k] = v;            // exact fp32, channel-major (refine)
        f16 h = (f16)v;                        // RTNE hi
        pn16h[(size_t)k * C + c] = h;
        pn16l[(size_t)k * C + c] = (f16)(v - (float)h);   // exact residual -> RTNE lo
    }
}

// ---------------------------------------------------------------------------
// Fast pass: compensated f16 MFMA argmax. 1024 threads = 16 waves; wave w
// owns protos [w*32, w*32+32) as 2 M-tiles; 64 positions as 4 N-sets of 16.
// Per tile per wave: 2t x 3q x 4s x 3 terms = 72 MFMAs.
// ---------------------------------------------------------------------------
__global__ __launch_bounds__(1024, 4) void sim_argmax_kernel(
        const float* __restrict__ x,
        const f16* __restrict__ pn16h,
        const f16* __restrict__ pn16l,
        int* __restrict__ out) {
    __shared__ __align__(16) f16 xth[CB * MT * 8];   // [cb][pos][8] hi, 12 KB
    __shared__ __align__(16) f16 xtl[CB * MT * 8];   // lo plane,     12 KB
    __shared__ float n2p[CB][MT];                    // ||x||^2 partials, 3 KB
    __shared__ float wm1[16][MT], wm2[16][MT];       // per-wave top-2,   8 KB

    const int tid = threadIdx.x;
    const int lane = tid & 63;
    const int w = tid >> 6;          // wave 0..15
    const int l15 = lane & 15;
    const int lg = lane >> 4;        // 0..3 (k-group)

    // ---- A fragments (32 protos/wave), hi+lo resident in VGPRs ----
    f16x8 afh[2][3], afl[2][3];
#pragma unroll
    for (int t = 0; t < 2; ++t)
#pragma unroll
        for (int q = 0; q < 3; ++q) {
            size_t off = (size_t)(w * 32 + t * 16 + l15) * C + q * 32 + lg * 8;
            afh[t][q] = *(const f16x8*)(pn16h + off);
            afl[t][q] = *(const f16x8*)(pn16l + off);
        }

    // staging role: wave w (<12) owns channel block w (8 ch); lane = pos
    const int m00 = blockIdx.x * (MT * ITERS_SIM);   // 110592 % 128 == 0:
    const int b = (m00 >= P_PER_B) ? 1 : 0;          // no batch straddle
    const float* xq = x + (size_t)b * (size_t)C * P_PER_B + (m00 - b * P_PER_B)
                    + (size_t)(w << 3) * P_PER_B + lane;   // valid when w < CB

#pragma unroll
    for (int it = 0; it < ITERS_SIM; ++it) {
        const int m0 = m00 + it * MT;

        __syncthreads();   // prev iter's xt/n2p/wm readers done

        // ---- stage: 8 ch/thread, one b128 store per plane ----
        if (w < CB) {
            float ss = 0.f;
            f16x8 vh, vl;
#pragma unroll
            for (int j = 0; j < 8; ++j) {
                float v = xq[(size_t)j * P_PER_B + it * MT];
                ss = fmaf(v, v, ss);
                f16 h = (f16)v;                   // RTNE hi
                vh[j] = h;
                vl[j] = (f16)(v - (float)h);      // exact residual
            }
            n2p[w][lane] = ss;
            *(f16x8*)(xth + ((w * MT + lane) << 3)) = vh;
            *(f16x8*)(xtl + ((w * MT + lane) << 3)) = vl;
        }
        __syncthreads();

        // ---- MFMA: D[proto][pos] = hh + lh + hl, 8 indep chains ----
        f32x4 acc[4][2];
#pragma unroll
        for (int s = 0; s < 4; ++s)
#pragma unroll
            for (int t = 0; t < 2; ++t)
                acc[s][t] = (f32x4){0.f, 0.f, 0.f, 0.f};
#pragma unroll
        for (int q = 0; q < 3; ++q) {
            const int cbase = ((q * 4 + lg) * MT) << 3;   // channel-block base
            f16x8 bh[4], bl[4];
#pragma unroll
            for (int s = 0; s < 4; ++s)
                bh[s] = *(const f16x8*)(xth + cbase + ((s * 16 + l15) << 3));
#pragma unroll
            for (int s = 0; s < 4; ++s)
#pragma unroll
                for (int t = 0; t < 2; ++t)
                    acc[s][t] = __builtin_amdgcn_mfma_f32_16x16x32_f16(
                        afh[t][q], bh[s], acc[s][t], 0, 0, 0);
#pragma unroll
            for (int s = 0; s < 4; ++s)
                bl[s] = *(const f16x8*)(xtl + cbase + ((s * 16 + l15) << 3));
#pragma unroll
            for (int s = 0; s < 4; ++s)
#pragma unroll
                for (int t = 0; t < 2; ++t)
                    acc[s][t] = __builtin_amdgcn_mfma_f32_16x16x32_f16(
                        afl[t][q], bh[s], acc[s][t], 0, 0, 0);
#pragma unroll
            for (int s = 0; s < 4; ++s)
#pragma unroll
                for (int t = 0; t < 2; ++t)
                    acc[s][t] = __builtin_amdgcn_mfma_f32_16x16x32_f16(
                        afh[t][q], bl[s], acc[s][t], 0, 0, 0);
        }

        // ---- branchless packed top-2 (k in low 9 mantissa bits) ----
        float m1[4], m2[4];
#pragma unroll
        for (int s = 0; s < 4; ++s) { m1[s] = -3.4e38f; m2[s] = -3.4e38f; }
        const int kb = w * 32 + (lg << 2);
#pragma unroll
        for (int t = 0; t < 2; ++t)
#pragma unroll
            for (int r = 0; r < 4; ++r) {
                const int kk = kb + t * 16 + r;   // folds to and_or + add
#pragma unroll
                for (int s = 0; s < 4; ++s) {
                    float v = acc[s][t][r];
                    float pk = __uint_as_float(
                        (__float_as_uint(v) & 0xFFFFFE00u) | (unsigned)kk);
                    m2[s] = fmaxf(m2[s], fminf(m1[s], pk));
                    m1[s] = fmaxf(m1[s], pk);
                }
            }

        // ---- merge the 4 k-groups sharing a position (masks 16, 32) ----
#pragma unroll
        for (int m = 16; m <= 32; m <<= 1)
#pragma unroll
            for (int s = 0; s < 4; ++s) {
                float o1 = __shfl_xor(m1[s], m);
                float o2 = __shfl_xor(m2[s], m);
                m2[s] = fmaxf(fmaxf(m2[s], o2), fminf(m1[s], o1));
                m1[s] = fmaxf(m1[s], o1);
            }
        if (lane < 16) {
#pragma unroll
            for (int s = 0; s < 4; ++s) {
                wm1[w][s * 16 + l15] = m1[s];
                wm2[w][s * 16 + l15] = m2[s];
            }
        }
        __syncthreads();

        // ---- final merge across 16 waves (disjoint proto sets) + tau ----
        if (tid < MT) {
            float n2 = 0.f;
#pragma unroll
            for (int g = 0; g < CB; ++g) n2 += n2p[g][tid];
            float b_ = wm1[0][tid], s_ = wm2[0][tid];
#pragma unroll
            for (int ww = 1; ww < 16; ++ww) {
                float o1 = wm1[ww][tid], o2 = wm2[ww][tid];
                s_ = fmaxf(fmaxf(s_, o2), fminf(b_, o1));
                b_ = fmaxf(b_, o1);
            }
            // tau >= 2*(pack 6.1e-5 + fast 2.2e-5 + numpy 1.8e-5) = 2.02e-4
            float tau = 2.6e-4f * sqrtf(n2) + 3e-5f;
            int k_ = (int)(__float_as_uint(b_) & 511u);
            out[m0 + tid] = (b_ - s_ < tau) ? (k_ | (int)0x80000000) : k_;
        }
    }
}

// ---------------------------------------------------------------------------
// Refine pass: bit-exact numpy-fp32 emulation of flagged positions.
// v2: the 4 waves of a block process flags w, w+4, ... in parallel (disjoint
// xn slices); per-proto math, norm chain, and argmax total-order are
// IDENTICAL to the validated serial version. 32-pos segments, grid 6912.
// ---------------------------------------------------------------------------
__global__ __launch_bounds__(256) void refine_kernel(
        const float* __restrict__ x,
        const float* __restrict__ pnT,
        int* __restrict__ out) {
    __shared__ int list[32];
    __shared__ int cnt;
    __shared__ float xn4[4][C];
    __shared__ float nrm4[4];

    const int tid = threadIdx.x;
    const int lane = tid & 63;
    const int w = tid >> 6;          // wave 0..3

    if (tid == 0) cnt = 0;
    __syncthreads();

    if (tid < 32) {
        int g = blockIdx.x * 32 + tid;
        if (out[g] < 0) {
            int i = atomicAdd(&cnt, 1);
            list[i] = g;
        }
    }
    __syncthreads();
    const int n = cnt;
    const int nmax = (n + 3) >> 2;

    for (int j = 0; j < nmax; ++j) {
        const int idx = j * 4 + w;
        const bool act = idx < n;
        const int gg = act ? list[idx] : list[0];
        const int b = (gg >= P_PER_B) ? 1 : 0;
        const int p = gg - b * P_PER_B;
        const float* xb = x + (size_t)b * (size_t)C * P_PER_B + p;

        if (act) {
            xn4[w][lane] = xb[(size_t)lane * P_PER_B];
            if (lane < C - 64) xn4[w][64 + lane] = xb[(size_t)(64 + lane) * P_PER_B];
        }
        __syncthreads();

        // numpy: norm over non-contiguous axis -> strictly sequential fp32
        if (act && lane == 0) {
            float a = __fmul_rn(xn4[w][0], xn4[w][0]);
            for (int c = 1; c < C; ++c)
                a = __fadd_rn(a, __fmul_rn(xn4[w][c], xn4[w][c]));
            nrm4[w] = fmaxf(__fsqrt_rn(a), 1e-12f);
        }
        __syncthreads();
        if (act) {
            xn4[w][lane] = __fdiv_rn(xn4[w][lane], nrm4[w]);
            if (lane < C - 64)
                xn4[w][64 + lane] = __fdiv_rn(xn4[w][64 + lane], nrm4[w]);
        }
        __syncthreads();

        if (act) {
            // einsum optimize=False: sequential fp32 mul+add, c ascending,
            // no FMA. Lane handles protos lane + 64*r, r = 0..7.
            float s[8];
#pragma unroll
            for (int r = 0; r < 8; ++r) s[r] = 0.f;
            for (int c = 0; c < C; ++c) {
                float xc = xn4[w][c];
                const float* pr = pnT + (size_t)c * K + lane;
#pragma unroll
                for (int r = 0; r < 8; ++r)
                    s[r] = __fadd_rn(s[r], __fmul_rn(xc, pr[r * 64]));
            }
            // per-lane best over r (k ascending: strict > keeps lowest k)
            float bv = s[0];
            int bk = lane;
#pragma unroll
            for (int r = 1; r < 8; ++r) {
                if (s[r] > bv) { bv = s[r]; bk = lane + r * 64; }
            }
            // wave-level argmax (exact compares, min-index tie-break)
#pragma unroll
            for (int off = 1; off < 64; off <<= 1) {
                float ov = __shfl_xor(bv, off);
                int oi = __shfl_xor(bk, off);
                if (ov > bv || (ov == bv && oi < bk)) { bv = ov; bk = oi; }
            }
            if (lane == 0) out[gg] = bk;
        }
    }
}

// ---------------------------------------------------------------------------
extern "C" void kernel_launch(void* const* d_in, const int* in_sizes, int n_in,
                              void* d_out, int out_size, void* d_ws, size_t ws_size,
                              hipStream_t stream) {
    const float* x = (const float*)d_in[0];      // [2,96,48,48,48] fp32
    const float* proto = (const float*)d_in[1];  // [512,96] fp32
    int* out = (int*)d_out;                      // [2,48,48,48] int32

    float* pnT = (float*)d_ws;                        // 96*512*4  = 196608 B
    f16* pn16h = (f16*)((char*)d_ws + 196608);        // 512*96*2  =  98304 B
    f16* pn16l = (f16*)((char*)d_ws + 294912);        // 512*96*2  =  98304 B

    prep_kernel<<<2, 256, 0, stream>>>(proto, pnT, pn16h, pn16l);
    sim_argmax_kernel<<<GRID_SIM, 1024, 0, stream>>>(x, pn16h, pn16l, out);
    refine_kernel<<<NPOS / 32, 256, 0, stream>>>(x, pnT, out);
}

// Round 12
// 236.394 us; speedup vs baseline: 1.6751x; 1.0716x over previous
//
#include <hip/hip_runtime.h>
#include <math.h>

#define C 96
#define K 512
#define P_PER_B 110592   // 48*48*48
#define NPOS 221184      // 2 * 110592
#define MT 64            // positions per tile (4 MFMA N-sets)
#define ITERS_SIM 2
#define GRID_SIM 1728    // 1728 blocks * 2 tiles * 64 pos = 221184
#define CB 12            // 8-channel blocks (C = 96 = 12*8)

// ---------------------------------------------------------------------------
// Round 12. Round-11 profile (253us, absmax=0): conflicts 9.29M -> 0 (cblock
// LDS worked) but sim flat at 118us with WRITE_SIZE 864KB -> 102MB = scratch
// spill. gfx950 unified VGPR+AGPR file: launch_bounds(1024,4) caps TOTAL at
// 128/thread; r11 demand (afh/afl 48 + acc 32 + bh/bl 32 + arch ~30) ~ 144
// -> spilled ~16 regs -> every acc chain waits on scratch (hbm 1.3TB/s of
// waste). Fixes:
//  1) stream afl per-q from L2 (pn16l 96KB L2-hot): A-resident 48 -> 24.
//  2) B loads in s-pairs (bh[2]+bl[2] = 16 live, was 32); hh/lh/hl at
//     dependency distance 4 MFMAs.
//  3) restore T14 prefetch: iter+1's 8 staging loads issued after the stage
//     barrier, HBM latency hides under MFMA+merge.
// Peak demand ~ 116 <= 128 -> no spill.
// Error budget unchanged from r10/r11 (absmax=0 validated twice): tau =
// 2.6e-4*||x|| + 3e-5; flagged (~0.8%) re-resolved bit-exactly by refine.
// ---------------------------------------------------------------------------

typedef _Float16 f16;
typedef _Float16 f16x8 __attribute__((ext_vector_type(8)));
typedef float f32x4 __attribute__((ext_vector_type(4)));

// Workspace: pnT[96][512] fp32 numpy-exact (192KB, refine) +
// pn16h[512][96] f16 hi (96KB) + pn16l[512][96] f16 lo (96KB). Total 384KB.

__global__ __launch_bounds__(256) void prep_kernel(const float* __restrict__ proto,
                                                   float* __restrict__ pnT,
                                                   f16* __restrict__ pn16h,
                                                   f16* __restrict__ pn16l) {
    int k = blockIdx.x * 256 + threadIdx.x;
    if (k >= K) return;
    const float* row = proto + k * C;
    // numpy pairwise_sum, n=96 <= blocksize: 8 accumulators + fixed combine
    float r[8];
#pragma unroll
    for (int j = 0; j < 8; ++j) r[j] = __fmul_rn(row[j], row[j]);
    for (int i = 8; i < C; i += 8) {
#pragma unroll
        for (int j = 0; j < 8; ++j)
            r[j] = __fadd_rn(r[j], __fmul_rn(row[i + j], row[i + j]));
    }
    float res = __fadd_rn(__fadd_rn(__fadd_rn(r[0], r[1]), __fadd_rn(r[2], r[3])),
                          __fadd_rn(__fadd_rn(r[4], r[5]), __fadd_rn(r[6], r[7])));
    float n = fmaxf(__fsqrt_rn(res), 1e-12f);
    for (int c = 0; c < C; ++c) {
        float v = __fdiv_rn(row[c], n);
        pnT[(size_t)c * K + k] = v;            // exact fp32, channel-major (refine)
        f16 h = (f16)v;                        // RTNE hi
        pn16h[(size_t)k * C + c] = h;
        pn16l[(size_t)k * C + c] = (f16)(v - (float)h);   // exact residual -> RTNE lo
    }
}

// ---------------------------------------------------------------------------
// Fast pass: compensated f16 MFMA argmax. 1024 threads = 16 waves; wave w
// owns protos [w*32, w*32+32) as 2 M-tiles; 64 positions as 4 N-sets of 16.
// Per tile per wave: 2t x 3q x 4s x 3 terms = 72 MFMAs. afh resident (24
// VGPR); afl streamed per-q from L2; B streamed per s-pair from LDS.
// ---------------------------------------------------------------------------
__global__ __launch_bounds__(1024, 4) void sim_argmax_kernel(
        const float* __restrict__ x,
        const f16* __restrict__ pn16h,
        const f16* __restrict__ pn16l,
        int* __restrict__ out) {
    __shared__ __align__(16) f16 xth[CB * MT * 8];   // [cb][pos][8] hi, 12 KB
    __shared__ __align__(16) f16 xtl[CB * MT * 8];   // lo plane,     12 KB
    __shared__ float n2p[CB][MT];                    // ||x||^2 partials, 3 KB
    __shared__ float wm1[16][MT], wm2[16][MT];       // per-wave top-2,   8 KB

    const int tid = threadIdx.x;
    const int lane = tid & 63;
    const int w = tid >> 6;          // wave 0..15
    const int l15 = lane & 15;
    const int lg = lane >> 4;        // 0..3 (k-group)

    // ---- A hi fragments (32 protos/wave) resident; lo streamed later ----
    const size_t aoff0 = (size_t)(w * 32 + l15) * C + lg * 8;
    const size_t aoff1 = aoff0 + (size_t)16 * C;
    f16x8 afh0[3], afh1[3];
#pragma unroll
    for (int q = 0; q < 3; ++q) {
        afh0[q] = *(const f16x8*)(pn16h + aoff0 + q * 32);
        afh1[q] = *(const f16x8*)(pn16h + aoff1 + q * 32);
    }

    // staging role: wave w (<12) owns channel block w (8 ch); lane = pos
    const int m00 = blockIdx.x * (MT * ITERS_SIM);   // 110592 % 128 == 0:
    const int b = (m00 >= P_PER_B) ? 1 : 0;          // no batch straddle
    const float* xq = x + (size_t)b * (size_t)C * P_PER_B + (m00 - b * P_PER_B)
                    + (size_t)(w << 3) * P_PER_B + lane;   // deref only if w < CB

    // prologue: tile 0's x into registers
    float fl[8];
    if (w < CB) {
#pragma unroll
        for (int j = 0; j < 8; ++j) fl[j] = xq[(size_t)j * P_PER_B];
    }

#pragma unroll
    for (int it = 0; it < ITERS_SIM; ++it) {
        const int m0 = m00 + it * MT;

        __syncthreads();   // prev iter's xt/n2p/wm readers done

        // ---- stage: 8 ch/thread, one b128 store per plane ----
        if (w < CB) {
            float ss = 0.f;
            f16x8 vh, vl;
#pragma unroll
            for (int j = 0; j < 8; ++j) {
                float v = fl[j];
                ss = fmaf(v, v, ss);
                f16 h = (f16)v;                   // RTNE hi
                vh[j] = h;
                vl[j] = (f16)(v - (float)h);      // exact residual
            }
            n2p[w][lane] = ss;
            *(f16x8*)(xth + ((w * MT + lane) << 3)) = vh;
            *(f16x8*)(xtl + ((w * MT + lane) << 3)) = vl;
        }
        __syncthreads();

        // ---- T14: issue next tile's loads now; consumed next iter ----
        if (w < CB && it + 1 < ITERS_SIM) {
#pragma unroll
            for (int j = 0; j < 8; ++j)
                fl[j] = xq[(size_t)j * P_PER_B + (it + 1) * MT];
        }

        // ---- MFMA: D[proto][pos] = hh + lh + hl ----
        f32x4 acc[4][2];
#pragma unroll
        for (int s = 0; s < 4; ++s)
#pragma unroll
            for (int t = 0; t < 2; ++t)
                acc[s][t] = (f32x4){0.f, 0.f, 0.f, 0.f};
#pragma unroll
        for (int q = 0; q < 3; ++q) {
            const int cbase = ((q * 4 + lg) * MT) << 3;   // channel-block base
            // stream A-lo for this q (L2-hot, 96 KB total)
            f16x8 al0 = *(const f16x8*)(pn16l + aoff0 + q * 32);
            f16x8 al1 = *(const f16x8*)(pn16l + aoff1 + q * 32);
#pragma unroll
            for (int sp = 0; sp < 2; ++sp) {              // s-pairs
                const int s0 = sp * 2, s1 = sp * 2 + 1;
                f16x8 b0 = *(const f16x8*)(xth + cbase + ((s0 * 16 + l15) << 3));
                f16x8 b1 = *(const f16x8*)(xth + cbase + ((s1 * 16 + l15) << 3));
                acc[s0][0] = __builtin_amdgcn_mfma_f32_16x16x32_f16(afh0[q], b0, acc[s0][0], 0, 0, 0);
                acc[s0][1] = __builtin_amdgcn_mfma_f32_16x16x32_f16(afh1[q], b0, acc[s0][1], 0, 0, 0);
                acc[s1][0] = __builtin_amdgcn_mfma_f32_16x16x32_f16(afh0[q], b1, acc[s1][0], 0, 0, 0);
                acc[s1][1] = __builtin_amdgcn_mfma_f32_16x16x32_f16(afh1[q], b1, acc[s1][1], 0, 0, 0);
                acc[s0][0] = __builtin_amdgcn_mfma_f32_16x16x32_f16(al0, b0, acc[s0][0], 0, 0, 0);
                acc[s0][1] = __builtin_amdgcn_mfma_f32_16x16x32_f16(al1, b0, acc[s0][1], 0, 0, 0);
                acc[s1][0] = __builtin_amdgcn_mfma_f32_16x16x32_f16(al0, b1, acc[s1][0], 0, 0, 0);
                acc[s1][1] = __builtin_amdgcn_mfma_f32_16x16x32_f16(al1, b1, acc[s1][1], 0, 0, 0);
                f16x8 c0 = *(const f16x8*)(xtl + cbase + ((s0 * 16 + l15) << 3));
                f16x8 c1 = *(const f16x8*)(xtl + cbase + ((s1 * 16 + l15) << 3));
                acc[s0][0] = __builtin_amdgcn_mfma_f32_16x16x32_f16(afh0[q], c0, acc[s0][0], 0, 0, 0);
                acc[s0][1] = __builtin_amdgcn_mfma_f32_16x16x32_f16(afh1[q], c0, acc[s0][1], 0, 0, 0);
                acc[s1][0] = __builtin_amdgcn_mfma_f32_16x16x32_f16(afh0[q], c1, acc[s1][0], 0, 0, 0);
                acc[s1][1] = __builtin_amdgcn_mfma_f32_16x16x32_f16(afh1[q], c1, acc[s1][1], 0, 0, 0);
            }
        }

        // ---- branchless packed top-2 (k in low 9 mantissa bits) ----
        float m1[4], m2[4];
#pragma unroll
        for (int s = 0; s < 4; ++s) { m1[s] = -3.4e38f; m2[s] = -3.4e38f; }
        const int kb = w * 32 + (lg << 2);
#pragma unroll
        for (int t = 0; t < 2; ++t)
#pragma unroll
            for (int r = 0; r < 4; ++r) {
                const int kk = kb + t * 16 + r;   // folds to and_or + add
#pragma unroll
                for (int s = 0; s < 4; ++s) {
                    float v = acc[s][t][r];
                    float pk = __uint_as_float(
                        (__float_as_uint(v) & 0xFFFFFE00u) | (unsigned)kk);
                    m2[s] = fmaxf(m2[s], fminf(m1[s], pk));
                    m1[s] = fmaxf(m1[s], pk);
                }
            }

        // ---- merge the 4 k-groups sharing a position (masks 16, 32) ----
#pragma unroll
        for (int m = 16; m <= 32; m <<= 1)
#pragma unroll
            for (int s = 0; s < 4; ++s) {
                float o1 = __shfl_xor(m1[s], m);
                float o2 = __shfl_xor(m2[s], m);
                m2[s] = fmaxf(fmaxf(m2[s], o2), fminf(m1[s], o1));
                m1[s] = fmaxf(m1[s], o1);
            }
        if (lane < 16) {
#pragma unroll
            for (int s = 0; s < 4; ++s) {
                wm1[w][s * 16 + l15] = m1[s];
                wm2[w][s * 16 + l15] = m2[s];
            }
        }
        __syncthreads();

        // ---- final merge across 16 waves (disjoint proto sets) + tau ----
        if (tid < MT) {
            float n2 = 0.f;
#pragma unroll
            for (int g = 0; g < CB; ++g) n2 += n2p[g][tid];
            float b_ = wm1[0][tid], s_ = wm2[0][tid];
#pragma unroll
            for (int ww = 1; ww < 16; ++ww) {
                float o1 = wm1[ww][tid], o2 = wm2[ww][tid];
                s_ = fmaxf(fmaxf(s_, o2), fminf(b_, o1));
                b_ = fmaxf(b_, o1);
            }
            // tau >= 2*(pack 6.1e-5 + fast 2.2e-5 + numpy 1.8e-5) = 2.02e-4
            float tau = 2.6e-4f * sqrtf(n2) + 3e-5f;
            int k_ = (int)(__float_as_uint(b_) & 511u);
            out[m0 + tid] = (b_ - s_ < tau) ? (k_ | (int)0x80000000) : k_;
        }
    }
}

// ---------------------------------------------------------------------------
// Refine pass (byte-identical to r11, validated): bit-exact numpy-fp32
// emulation of flagged positions; 4-wave-parallel; 32-pos segments.
// ---------------------------------------------------------------------------
__global__ __launch_bounds__(256) void refine_kernel(
        const float* __restrict__ x,
        const float* __restrict__ pnT,
        int* __restrict__ out) {
    __shared__ int list[32];
    __shared__ int cnt;
    __shared__ float xn4[4][C];
    __shared__ float nrm4[4];

    const int tid = threadIdx.x;
    const int lane = tid & 63;
    const int w = tid >> 6;          // wave 0..3

    if (tid == 0) cnt = 0;
    __syncthreads();

    if (tid < 32) {
        int g = blockIdx.x * 32 + tid;
        if (out[g] < 0) {
            int i = atomicAdd(&cnt, 1);
            list[i] = g;
        }
    }
    __syncthreads();
    const int n = cnt;
    const int nmax = (n + 3) >> 2;

    for (int j = 0; j < nmax; ++j) {
        const int idx = j * 4 + w;
        const bool act = idx < n;
        const int gg = act ? list[idx] : list[0];
        const int b = (gg >= P_PER_B) ? 1 : 0;
        const int p = gg - b * P_PER_B;
        const float* xb = x + (size_t)b * (size_t)C * P_PER_B + p;

        if (act) {
            xn4[w][lane] = xb[(size_t)lane * P_PER_B];
            if (lane < C - 64) xn4[w][64 + lane] = xb[(size_t)(64 + lane) * P_PER_B];
        }
        __syncthreads();

        // numpy: norm over non-contiguous axis -> strictly sequential fp32
        if (act && lane == 0) {
            float a = __fmul_rn(xn4[w][0], xn4[w][0]);
            for (int c = 1; c < C; ++c)
                a = __fadd_rn(a, __fmul_rn(xn4[w][c], xn4[w][c]));
            nrm4[w] = fmaxf(__fsqrt_rn(a), 1e-12f);
        }
        __syncthreads();
        if (act) {
            xn4[w][lane] = __fdiv_rn(xn4[w][lane], nrm4[w]);
            if (lane < C - 64)
                xn4[w][64 + lane] = __fdiv_rn(xn4[w][64 + lane], nrm4[w]);
        }
        __syncthreads();

        if (act) {
            // einsum optimize=False: sequential fp32 mul+add, c ascending,
            // no FMA. Lane handles protos lane + 64*r, r = 0..7.
            float s[8];
#pragma unroll
            for (int r = 0; r < 8; ++r) s[r] = 0.f;
            for (int c = 0; c < C; ++c) {
                float xc = xn4[w][c];
                const float* pr = pnT + (size_t)c * K + lane;
#pragma unroll
                for (int r = 0; r < 8; ++r)
                    s[r] = __fadd_rn(s[r], __fmul_rn(xc, pr[r * 64]));
            }
            // per-lane best over r (k ascending: strict > keeps lowest k)
            float bv = s[0];
            int bk = lane;
#pragma unroll
            for (int r = 1; r < 8; ++r) {
                if (s[r] > bv) { bv = s[r]; bk = lane + r * 64; }
            }
            // wave-level argmax (exact compares, min-index tie-break)
#pragma unroll
            for (int off = 1; off < 64; off <<= 1) {
                float ov = __shfl_xor(bv, off);
                int oi = __shfl_xor(bk, off);
                if (ov > bv || (ov == bv && oi < bk)) { bv = ov; bk = oi; }
            }
            if (lane == 0) out[gg] = bk;
        }
    }
}

// ---------------------------------------------------------------------------
extern "C" void kernel_launch(void* const* d_in, const int* in_sizes, int n_in,
                              void* d_out, int out_size, void* d_ws, size_t ws_size,
                              hipStream_t stream) {
    const float* x = (const float*)d_in[0];      // [2,96,48,48,48] fp32
    const float* proto = (const float*)d_in[1];  // [512,96] fp32
    int* out = (int*)d_out;                      // [2,48,48,48] int32

    float* pnT = (float*)d_ws;                        // 96*512*4  = 196608 B
    f16* pn16h = (f16*)((char*)d_ws + 196608);        // 512*96*2  =  98304 B
    f16* pn16l = (f16*)((char*)d_ws + 294912);        // 512*96*2  =  98304 B

    prep_kernel<<<2, 256, 0, stream>>>(proto, pnT, pn16h, pn16l);
    sim_argmax_kernel<<<GRID_SIM, 1024, 0, stream>>>(x, pn16h, pn16l, out);
    refine_kernel<<<NPOS / 32, 256, 0, stream>>>(x, pnT, out);
}